// Round 5
// baseline (367.948 us; speedup 1.0000x reference)
//
#include <hip/hip_runtime.h>
#include <math.h>

#define N_NODES 50000
#define N_EDGES 800000
#define ET (N_EDGES + N_NODES)   // 850000 edges incl. self-loops
#define D 256
#define NEG_SLOPE 0.2f
#define SCAN_ITEMS 1024
#define NB_SCAN ((N_NODES + SCAN_ITEMS - 1) / SCAN_ITEMS)   // 49

typedef __attribute__((ext_vector_type(8))) _Float16 half8;     // MFMA A/B frag (8 f16)
typedef __attribute__((ext_vector_type(8))) unsigned short ushort8;
typedef __attribute__((ext_vector_type(4))) unsigned short us4;
typedef __attribute__((ext_vector_type(4))) float f32x4;

__device__ inline unsigned short f2h(float f) {
    union { _Float16 h; unsigned short u; } v; v.h = (_Float16)f; return v.u;
}
__device__ inline float h2f(unsigned short u) {
    union { unsigned short u; _Float16 h; } v; v.u = u; return (float)v.h;
}

// ---------------- edge format probe (int32 vs int64 edge_index) ----------------
__global__ void detect_fmt(const int* __restrict__ eidx, int* __restrict__ flag) {
    int i = blockIdx.x * 256 + threadIdx.x;
    if (i < 1024 && eidx[2 * i + 1] != 0) atomicOr(flag, 1);  // nonzero odd word -> int32
}

__device__ inline int edge_src(const int* eidx, int is32, int e) {
    if (e >= N_EDGES) return e - N_EDGES;
    return is32 ? eidx[e] : eidx[2 * e];
}
__device__ inline int edge_dst(const int* eidx, int is32, int e) {
    if (e >= N_EDGES) return e - N_EDGES;
    return is32 ? eidx[N_EDGES + e] : eidx[2 * (N_EDGES + e)];
}

// ---------------- CSR build ----------------
__global__ void count_deg(const int* __restrict__ eidx, const int* __restrict__ flag,
                          int* __restrict__ deg) {
    int e = blockIdx.x * 256 + threadIdx.x;
    if (e >= ET) return;
    int is32 = *flag;
    atomicAdd(&deg[edge_dst(eidx, is32, e)], 1);
}

__global__ __launch_bounds__(256) void scan_block_sums(const int* __restrict__ deg,
                                                       int* __restrict__ bsum) {
    __shared__ int wsums[4];
    int base = blockIdx.x * SCAN_ITEMS + threadIdx.x * 4;
    int s = 0;
    #pragma unroll
    for (int k = 0; k < 4; ++k) { int i = base + k; if (i < N_NODES) s += deg[i]; }
    for (int d = 1; d < 64; d <<= 1) s += __shfl_xor(s, d, 64);
    int lane = threadIdx.x & 63, wid = threadIdx.x >> 6;
    if (lane == 0) wsums[wid] = s;
    __syncthreads();
    if (threadIdx.x == 0) bsum[blockIdx.x] = wsums[0] + wsums[1] + wsums[2] + wsums[3];
}

__global__ void scan_carry(const int* __restrict__ bsum, int* __restrict__ carry,
                           int* __restrict__ off) {
    if (threadIdx.x == 0) {
        int run = 0;
        for (int b = 0; b < NB_SCAN; ++b) { carry[b] = run; run += bsum[b]; }
        off[N_NODES] = ET;
    }
}

__global__ __launch_bounds__(256) void scan_write(const int* __restrict__ deg,
                                                  const int* __restrict__ carry,
                                                  int* __restrict__ off,
                                                  int* __restrict__ cur) {
    __shared__ int wsums[4];
    int base = blockIdx.x * SCAN_ITEMS + threadIdx.x * 4;
    int v[4]; int s = 0;
    #pragma unroll
    for (int k = 0; k < 4; ++k) { int i = base + k; v[k] = (i < N_NODES) ? deg[i] : 0; s += v[k]; }
    int inc = s;
    int lane = threadIdx.x & 63, wid = threadIdx.x >> 6;
    for (int d = 1; d < 64; d <<= 1) { int u = __shfl_up(inc, d, 64); if (lane >= d) inc += u; }
    if (lane == 63) wsums[wid] = inc;
    __syncthreads();
    int woff = 0;
    for (int w = 0; w < wid; ++w) woff += wsums[w];
    int excl = woff + inc - s + carry[blockIdx.x];
    #pragma unroll
    for (int k = 0; k < 4; ++k) {
        int i = base + k;
        if (i < N_NODES) { off[i] = excl; cur[i] = excl; excl += v[k]; }
    }
}

__global__ void scatter_edges(const int* __restrict__ eidx, const int* __restrict__ flag,
                              int* __restrict__ cur, int* __restrict__ srcs) {
    int e = blockIdx.x * 256 + threadIdx.x;
    if (e >= ET) return;
    int is32 = *flag;
    int src = edge_src(eidx, is32, e);
    int dst = edge_dst(eidx, is32, e);
    int pos = atomicAdd(&cur[dst], 1);
    srcs[pos] = src;
}

// W[K][256] -> Wt[256][K] f16
__global__ void conv_w_t(const float* __restrict__ W, unsigned short* __restrict__ Wt, int K) {
    int k = blockIdx.x, n = threadIdx.x;
    Wt[(size_t)n * K + k] = f2h(W[(size_t)k * D + n]);
}

// ---------------- fused f16 MFMA GEMM + attention scores ----------------
// C[M x 256] = A[M x K] * Bt^T (C stored f16). Epilogue computes per-row dots
// with a_src/a_dst from the f32 accumulators and atomicAdds into es/ed.
template <bool AF32, int HEADS>
__global__ __launch_bounds__(256) void gemm_fused(const void* __restrict__ Ain,
                                                  const unsigned short* __restrict__ Bt,
                                                  unsigned short* __restrict__ C,
                                                  const float* __restrict__ a_src,
                                                  const float* __restrict__ a_dst,
                                                  float* __restrict__ es,
                                                  float* __restrict__ ed,
                                                  int M, int K) {
    __shared__ __align__(16) unsigned short As[128][40];  // [row][k], pad to 40
    __shared__ __align__(16) unsigned short Bs[64][40];   // [n][k]
    int t = threadIdx.x, lane = t & 63, wid = t >> 6;
    int wm = wid >> 1, wn = wid & 1;                      // 2x2 waves, wave tile 64x32
    int row0 = blockIdx.y * 128, col0 = blockIdx.x * 64;
    f32x4 acc[4][2] = {};
    int ar = t >> 1, ap = t & 1;                          // A: 2 thr/row, 16 elems each
    int bn = t >> 2, bp = t & 3;                          // B: 4 thr/row, 8 elems each
    for (int k0 = 0; k0 < K; k0 += 32) {
        ushort8 a0 = {0,0,0,0,0,0,0,0}, a1 = {0,0,0,0,0,0,0,0};
        if (row0 + ar < M) {
            if constexpr (AF32) {
                const float4* p = (const float4*)&((const float*)Ain)[(size_t)(row0 + ar) * K + k0 + ap * 16];
                float4 f0 = p[0], f1 = p[1], f2 = p[2], f3 = p[3];
                a0[0]=f2h(f0.x); a0[1]=f2h(f0.y); a0[2]=f2h(f0.z); a0[3]=f2h(f0.w);
                a0[4]=f2h(f1.x); a0[5]=f2h(f1.y); a0[6]=f2h(f1.z); a0[7]=f2h(f1.w);
                a1[0]=f2h(f2.x); a1[1]=f2h(f2.y); a1[2]=f2h(f2.z); a1[3]=f2h(f2.w);
                a1[4]=f2h(f3.x); a1[5]=f2h(f3.y); a1[6]=f2h(f3.z); a1[7]=f2h(f3.w);
            } else {
                const ushort8* p = (const ushort8*)&((const unsigned short*)Ain)[(size_t)(row0 + ar) * K + k0 + ap * 16];
                a0 = p[0]; a1 = p[1];
            }
        }
        *(ushort8*)&As[ar][ap * 16]     = a0;
        *(ushort8*)&As[ar][ap * 16 + 8] = a1;
        *(ushort8*)&Bs[bn][bp * 8] = *(const ushort8*)&Bt[(size_t)(col0 + bn) * K + k0 + bp * 8];
        __syncthreads();
        half8 af[4], bg[2];
        #pragma unroll
        for (int mi = 0; mi < 4; ++mi)
            af[mi] = *(const half8*)&As[wm * 64 + mi * 16 + (lane & 15)][(lane >> 4) * 8];
        #pragma unroll
        for (int ni = 0; ni < 2; ++ni)
            bg[ni] = *(const half8*)&Bs[wn * 32 + ni * 16 + (lane & 15)][(lane >> 4) * 8];
        #pragma unroll
        for (int mi = 0; mi < 4; ++mi)
            #pragma unroll
            for (int ni = 0; ni < 2; ++ni)
                acc[mi][ni] = __builtin_amdgcn_mfma_f32_16x16x32_f16(af[mi], bg[ni], acc[mi][ni], 0, 0, 0);
        __syncthreads();
    }
    // epilogue: C store + fused scores
    int c15 = lane & 15;
    float as0 = a_src[col0 + wn * 32 + c15];
    float as1 = a_src[col0 + wn * 32 + 16 + c15];
    float ad0 = a_dst[col0 + wn * 32 + c15];
    float ad1 = a_dst[col0 + wn * 32 + 16 + c15];
    int head = (HEADS == 8) ? (blockIdx.x * 2 + wn) : 0;
    #pragma unroll
    for (int mi = 0; mi < 4; ++mi) {
        int rowb = row0 + wm * 64 + mi * 16 + ((lane >> 4) << 2);
        #pragma unroll
        for (int ni = 0; ni < 2; ++ni) {
            int col = col0 + wn * 32 + ni * 16 + c15;
            #pragma unroll
            for (int r = 0; r < 4; ++r)
                if (rowb + r < M) C[(size_t)(rowb + r) * D + col] = f2h(acc[mi][ni][r]);
        }
        #pragma unroll
        for (int r = 0; r < 4; ++r) {
            float pes = acc[mi][0][r] * as0 + acc[mi][1][r] * as1;
            float ped = acc[mi][0][r] * ad0 + acc[mi][1][r] * ad1;
            #pragma unroll
            for (int msk = 1; msk < 16; msk <<= 1) {
                pes += __shfl_xor(pes, msk, 64);
                ped += __shfl_xor(ped, msk, 64);
            }
            if (c15 == 0 && rowb + r < M) {
                atomicAdd(&es[(size_t)(rowb + r) * HEADS + head], pes);
                atomicAdd(&ed[(size_t)(rowb + r) * HEADS + head], ped);
            }
        }
    }
}

// ---------------- per-edge alpha (f16) via online softmax; one wave per node ----------------
template <int H>
__global__ __launch_bounds__(256) void softmax_alpha(const float* __restrict__ es,
                                                     const float* __restrict__ ed,
                                                     const int* __restrict__ off,
                                                     const int* __restrict__ srcs,
                                                     unsigned short* __restrict__ alpha16) {
    int n = blockIdx.x * 4 + (threadIdx.x >> 6);
    if (n >= N_NODES) return;
    int lane = threadIdx.x & 63;
    int begin = off[n], end = off[n + 1];
    int j  = (H == 8) ? (lane >> 3) : lane;
    int hd = (H == 8) ? (lane & 7) : 0;
    const int JS = (H == 8) ? 8 : 64;
    float edn = ed[(size_t)n * H + hd];
    float m = -1e30f, s = 0.f;
    for (int i = begin + j; i < end; i += JS) {
        float e = es[(size_t)srcs[i] * H + hd] + edn;
        e = e > 0.f ? e : NEG_SLOPE * e;
        float nm = fmaxf(m, e);
        s = s * __expf(m - nm) + __expf(e - nm);
        m = nm;
    }
    #pragma unroll
    for (int mask = (H == 8) ? 8 : 1; mask < 64; mask <<= 1) {
        float om = __shfl_xor(m, mask, 64);
        float os = __shfl_xor(s, mask, 64);
        float nm = fmaxf(m, om);
        s = s * __expf(m - nm) + os * __expf(om - nm);
        m = nm;
    }
    float inv_s = 1.f / s;
    for (int i = begin + j; i < end; i += JS) {
        float e = es[(size_t)srcs[i] * H + hd] + edn;
        e = e > 0.f ? e : NEG_SLOPE * e;
        alpha16[(size_t)i * H + hd] = f2h(__expf(e - m) * inv_s);
    }
}

// ---------------- weighted gather of f16 h + bias + elu; one wave per node ----------------
template <int H, bool OUT_F16>
__global__ __launch_bounds__(256) void gather_agg(const unsigned short* __restrict__ h,
                                                  const unsigned short* __restrict__ alpha16,
                                                  const int* __restrict__ off,
                                                  const int* __restrict__ srcs,
                                                  const float* __restrict__ bias,
                                                  void* __restrict__ outv) {
    int n = blockIdx.x * 4 + (threadIdx.x >> 6);
    if (n >= N_NODES) return;
    int lane = threadIdx.x & 63;
    int begin = off[n], end = off[n + 1];
    int hsel = (H == 8) ? (lane >> 3) : 0;
    float ax = 0.f, ay = 0.f, az = 0.f, aw = 0.f;
    int i = begin;
    for (; i + 3 < end; i += 4) {
        int s0 = srcs[i], s1 = srcs[i + 1], s2 = srcs[i + 2], s3 = srcs[i + 3];
        float w0 = h2f(alpha16[(size_t)i * H + hsel]);
        float w1 = h2f(alpha16[(size_t)(i + 1) * H + hsel]);
        float w2 = h2f(alpha16[(size_t)(i + 2) * H + hsel]);
        float w3 = h2f(alpha16[(size_t)(i + 3) * H + hsel]);
        us4 v0 = *(const us4*)&h[(size_t)s0 * D + lane * 4];
        us4 v1 = *(const us4*)&h[(size_t)s1 * D + lane * 4];
        us4 v2 = *(const us4*)&h[(size_t)s2 * D + lane * 4];
        us4 v3 = *(const us4*)&h[(size_t)s3 * D + lane * 4];
        ax += h2f(v0.x) * w0 + h2f(v1.x) * w1 + h2f(v2.x) * w2 + h2f(v3.x) * w3;
        ay += h2f(v0.y) * w0 + h2f(v1.y) * w1 + h2f(v2.y) * w2 + h2f(v3.y) * w3;
        az += h2f(v0.z) * w0 + h2f(v1.z) * w1 + h2f(v2.z) * w2 + h2f(v3.z) * w3;
        aw += h2f(v0.w) * w0 + h2f(v1.w) * w1 + h2f(v2.w) * w2 + h2f(v3.w) * w3;
    }
    for (; i < end; ++i) {
        int s0 = srcs[i];
        float w0 = h2f(alpha16[(size_t)i * H + hsel]);
        us4 v0 = *(const us4*)&h[(size_t)s0 * D + lane * 4];
        ax += h2f(v0.x) * w0; ay += h2f(v0.y) * w0; az += h2f(v0.z) * w0; aw += h2f(v0.w) * w0;
    }
    float4 b = *(const float4*)&bias[lane * 4];
    float r0 = ax + b.x, r1 = ay + b.y, r2 = az + b.z, r3 = aw + b.w;
    r0 = r0 > 0.f ? r0 : __expf(r0) - 1.f;
    r1 = r1 > 0.f ? r1 : __expf(r1) - 1.f;
    r2 = r2 > 0.f ? r2 : __expf(r2) - 1.f;
    r3 = r3 > 0.f ? r3 : __expf(r3) - 1.f;
    if (OUT_F16) {
        us4 o; o.x = f2h(r0); o.y = f2h(r1); o.z = f2h(r2); o.w = f2h(r3);
        *(us4*)&((unsigned short*)outv)[(size_t)n * D + lane * 4] = o;
    } else {
        *(float4*)&((float*)outv)[(size_t)n * D + lane * 4] = make_float4(r0, r1, r2, r3);
    }
}

// ---------------- launch ----------------
extern "C" void kernel_launch(void* const* d_in, const int* in_sizes, int n_in,
                              void* d_out, int out_size, void* d_ws, size_t ws_size,
                              hipStream_t stream) {
    const float* x        = (const float*)d_in[0];
    const int*   eidx     = (const int*)d_in[1];
    const float* W1       = (const float*)d_in[2];
    const float* att_src1 = (const float*)d_in[3];
    const float* att_dst1 = (const float*)d_in[4];
    const float* b1       = (const float*)d_in[5];
    const float* W2       = (const float*)d_in[6];
    const float* att_src2 = (const float*)d_in[7];
    const float* att_dst2 = (const float*)d_in[8];
    const float* b2       = (const float*)d_in[9];
    float* out = (float*)d_out;

    char* ws = (char*)d_ws;
    size_t o = 0;
    auto take = [&](size_t bytes) { char* p = ws + o; o = (o + bytes + 255) & ~(size_t)255; return p; };
    unsigned short* hb    = (unsigned short*)take((size_t)N_NODES * D * 2);   // 25.6 MB
    unsigned short* zb    = (unsigned short*)take((size_t)N_NODES * D * 2);   // 25.6 MB
    unsigned short* W1t   = (unsigned short*)take((size_t)D * 128 * 2);
    unsigned short* W2t   = (unsigned short*)take((size_t)D * D * 2);
    unsigned short* alpha16 = (unsigned short*)take((size_t)ET * 8 * 2);      // 13.6 MB
    size_t es_begin = o;
    float* es1  = (float*)take((size_t)N_NODES * 8 * 4);
    float* ed1  = (float*)take((size_t)N_NODES * 8 * 4);
    float* es2  = (float*)take((size_t)N_NODES * 4);
    float* ed2  = (float*)take((size_t)N_NODES * 4);
    size_t es_end = o;
    int*   off  = (int*)take((size_t)(N_NODES + 1) * 4);
    int*   cur  = (int*)take((size_t)N_NODES * 4);
    int*   srcs = (int*)take((size_t)ET * 4);
    int*   deg  = (int*)take((size_t)N_NODES * 4);
    int*   bsum = (int*)take(256);
    int*   carry= (int*)take(256);
    int*   flag = (int*)take(256);

    hipMemsetAsync(deg, 0, (size_t)N_NODES * 4, stream);
    hipMemsetAsync(flag, 0, 4, stream);
    hipMemsetAsync(ws + es_begin, 0, es_end - es_begin, stream);   // es1/ed1/es2/ed2 (atomic accum)

    const int EB = (ET + 255) / 256;
    detect_fmt<<<4, 256, 0, stream>>>(eidx, flag);
    count_deg<<<EB, 256, 0, stream>>>(eidx, flag, deg);
    scan_block_sums<<<NB_SCAN, 256, 0, stream>>>(deg, bsum);
    scan_carry<<<1, 64, 0, stream>>>(bsum, carry, off);
    scan_write<<<NB_SCAN, 256, 0, stream>>>(deg, carry, off, cur);
    scatter_edges<<<EB, 256, 0, stream>>>(eidx, flag, cur, srcs);

    conv_w_t<<<128, 256, 0, stream>>>(W1, W1t, 128);
    conv_w_t<<<256, 256, 0, stream>>>(W2, W2t, 256);

    const int NBLK = (N_NODES + 3) / 4;
    const dim3 GG(4, (N_NODES + 127) / 128);
    // ---- layer 1 ----
    gemm_fused<true, 8><<<GG, 256, 0, stream>>>(x, W1t, hb, att_src1, att_dst1, es1, ed1, N_NODES, 128);
    softmax_alpha<8><<<NBLK, 256, 0, stream>>>(es1, ed1, off, srcs, alpha16);
    gather_agg<8, true><<<NBLK, 256, 0, stream>>>(hb, alpha16, off, srcs, b1, zb);
    // ---- layer 2 ----
    gemm_fused<false, 1><<<GG, 256, 0, stream>>>(zb, W2t, hb, att_src2, att_dst2, es2, ed2, N_NODES, 256);
    softmax_alpha<1><<<NBLK, 256, 0, stream>>>(es2, ed2, off, srcs, alpha16);
    gather_agg<1, false><<<NBLK, 256, 0, stream>>>(hb, alpha16, off, srcs, b2, out);
}

// Round 6
// 352.489 us; speedup vs baseline: 1.0439x; 1.0439x over previous
//
#include <hip/hip_runtime.h>
#include <math.h>

#define N_NODES 50000
#define N_EDGES 800000
#define ET (N_EDGES + N_NODES)   // 850000 edges incl. self-loops
#define D 256
#define NEG_SLOPE 0.2f
#define SCAN_ITEMS 1024
#define NB_SCAN ((N_NODES + SCAN_ITEMS - 1) / SCAN_ITEMS)   // 49

typedef __attribute__((ext_vector_type(8))) _Float16 half8;     // MFMA A/B frag (8 f16)
typedef __attribute__((ext_vector_type(8))) unsigned short ushort8;
typedef __attribute__((ext_vector_type(4))) unsigned short us4;
typedef __attribute__((ext_vector_type(4))) float f32x4;

__device__ inline unsigned short f2h(float f) {
    union { _Float16 h; unsigned short u; } v; v.h = (_Float16)f; return v.u;
}
__device__ inline float h2f(unsigned short u) {
    union { unsigned short u; _Float16 h; } v; v.u = u; return (float)v.h;
}

// ---------------- edge format probe (int32 vs int64 edge_index) ----------------
__global__ void detect_fmt(const int* __restrict__ eidx, int* __restrict__ flag) {
    int i = blockIdx.x * 256 + threadIdx.x;
    if (i < 1024 && eidx[2 * i + 1] != 0) atomicOr(flag, 1);  // nonzero odd word -> int32
}

__device__ inline int edge_src(const int* eidx, int is32, int e) {
    if (e >= N_EDGES) return e - N_EDGES;
    return is32 ? eidx[e] : eidx[2 * e];
}
__device__ inline int edge_dst(const int* eidx, int is32, int e) {
    if (e >= N_EDGES) return e - N_EDGES;
    return is32 ? eidx[N_EDGES + e] : eidx[2 * (N_EDGES + e)];
}

// ---------------- CSR build ----------------
__global__ void count_deg(const int* __restrict__ eidx, const int* __restrict__ flag,
                          int* __restrict__ deg) {
    int e = blockIdx.x * 256 + threadIdx.x;
    if (e >= ET) return;
    int is32 = *flag;
    atomicAdd(&deg[edge_dst(eidx, is32, e)], 1);
}

__global__ __launch_bounds__(256) void scan_block_sums(const int* __restrict__ deg,
                                                       int* __restrict__ bsum) {
    __shared__ int wsums[4];
    int base = blockIdx.x * SCAN_ITEMS + threadIdx.x * 4;
    int s = 0;
    #pragma unroll
    for (int k = 0; k < 4; ++k) { int i = base + k; if (i < N_NODES) s += deg[i]; }
    for (int d = 1; d < 64; d <<= 1) s += __shfl_xor(s, d, 64);
    int lane = threadIdx.x & 63, wid = threadIdx.x >> 6;
    if (lane == 0) wsums[wid] = s;
    __syncthreads();
    if (threadIdx.x == 0) bsum[blockIdx.x] = wsums[0] + wsums[1] + wsums[2] + wsums[3];
}

__global__ void scan_carry(const int* __restrict__ bsum, int* __restrict__ carry,
                           int* __restrict__ off) {
    if (threadIdx.x == 0) {
        int run = 0;
        for (int b = 0; b < NB_SCAN; ++b) { carry[b] = run; run += bsum[b]; }
        off[N_NODES] = ET;
    }
}

__global__ __launch_bounds__(256) void scan_write(const int* __restrict__ deg,
                                                  const int* __restrict__ carry,
                                                  int* __restrict__ off,
                                                  int* __restrict__ cur) {
    __shared__ int wsums[4];
    int base = blockIdx.x * SCAN_ITEMS + threadIdx.x * 4;
    int v[4]; int s = 0;
    #pragma unroll
    for (int k = 0; k < 4; ++k) { int i = base + k; v[k] = (i < N_NODES) ? deg[i] : 0; s += v[k]; }
    int inc = s;
    int lane = threadIdx.x & 63, wid = threadIdx.x >> 6;
    for (int d = 1; d < 64; d <<= 1) { int u = __shfl_up(inc, d, 64); if (lane >= d) inc += u; }
    if (lane == 63) wsums[wid] = inc;
    __syncthreads();
    int woff = 0;
    for (int w = 0; w < wid; ++w) woff += wsums[w];
    int excl = woff + inc - s + carry[blockIdx.x];
    #pragma unroll
    for (int k = 0; k < 4; ++k) {
        int i = base + k;
        if (i < N_NODES) { off[i] = excl; cur[i] = excl; excl += v[k]; }
    }
}

__global__ void scatter_edges(const int* __restrict__ eidx, const int* __restrict__ flag,
                              int* __restrict__ cur, int* __restrict__ srcs) {
    int e = blockIdx.x * 256 + threadIdx.x;
    if (e >= ET) return;
    int is32 = *flag;
    int src = edge_src(eidx, is32, e);
    int dst = edge_dst(eidx, is32, e);
    int pos = atomicAdd(&cur[dst], 1);
    srcs[pos] = src;
}

// ---------------- conversions / precompute ----------------
__global__ __launch_bounds__(256) void conv_f32_f16(const float* __restrict__ in,
                                                    unsigned short* __restrict__ outh,
                                                    int n4) {
    int i = blockIdx.x * 256 + threadIdx.x;
    if (i >= n4) return;
    float4 v = *(const float4*)&in[(size_t)i * 4];
    us4 o; o.x = f2h(v.x); o.y = f2h(v.y); o.z = f2h(v.z); o.w = f2h(v.w);
    *(us4*)&outh[(size_t)i * 4] = o;
}

// W[K][256] -> Wt[256][K] f16
__global__ void conv_w_t(const float* __restrict__ W, unsigned short* __restrict__ Wt, int K) {
    int k = blockIdx.x, n = threadIdx.x;
    Wt[(size_t)n * K + k] = f2h(W[(size_t)k * D + n]);
}

// was2[k] = sum_j W2[k][j]*a_src2[j]; wad2 likewise (layer-2 score vectors in input space)
__global__ void wvec2(const float* __restrict__ W2, const float* __restrict__ as2,
                      const float* __restrict__ ad2, float* __restrict__ was2,
                      float* __restrict__ wad2) {
    int k = threadIdx.x;   // one block of 256
    float s = 0.f, d = 0.f;
    for (int j = 0; j < D; ++j) {
        float w = W2[(size_t)k * D + j];
        s += w * as2[j];
        d += w * ad2[j];
    }
    was2[k] = s; wad2[k] = d;
}

// ---------------- f16 MFMA GEMM, 128x128 tile ----------------
// C[M x 256] = A[M x K] * Bt^T (Bt is [256][K] f16).
// EPI=false: store C f16.  EPI=true: store elu(acc + bias) as f32.
template <bool EPI>
__global__ __launch_bounds__(256) void gemm_f16(const unsigned short* __restrict__ A,
                                                const unsigned short* __restrict__ Bt,
                                                void* __restrict__ Cout,
                                                const float* __restrict__ bias,
                                                int M, int K) {
    __shared__ __align__(16) unsigned short As[128][40];  // [row][k], pad to 40
    __shared__ __align__(16) unsigned short Bs[128][40];  // [n][k]
    int t = threadIdx.x, lane = t & 63, wid = t >> 6;
    int wm = wid >> 1, wn = wid & 1;                      // 2x2 waves, wave tile 64x64
    int row0 = blockIdx.y * 128, col0 = blockIdx.x * 128;
    int c15 = lane & 15;
    f32x4 acc[4][4] = {};
    int ar = t >> 1, ap = t & 1;                          // A/B: 2 thr/row, 16 elems each
    for (int k0 = 0; k0 < K; k0 += 32) {
        ushort8 a0 = {0,0,0,0,0,0,0,0}, a1 = {0,0,0,0,0,0,0,0};
        if (row0 + ar < M) {
            const ushort8* p = (const ushort8*)&A[(size_t)(row0 + ar) * K + k0 + ap * 16];
            a0 = p[0]; a1 = p[1];
        }
        *(ushort8*)&As[ar][ap * 16]     = a0;
        *(ushort8*)&As[ar][ap * 16 + 8] = a1;
        const ushort8* q = (const ushort8*)&Bt[(size_t)(col0 + ar) * K + k0 + ap * 16];
        *(ushort8*)&Bs[ar][ap * 16]     = q[0];
        *(ushort8*)&Bs[ar][ap * 16 + 8] = q[1];
        __syncthreads();
        half8 af[4], bg[4];
        #pragma unroll
        for (int mi = 0; mi < 4; ++mi)
            af[mi] = *(const half8*)&As[wm * 64 + mi * 16 + c15][(lane >> 4) * 8];
        #pragma unroll
        for (int ni = 0; ni < 4; ++ni)
            bg[ni] = *(const half8*)&Bs[wn * 64 + ni * 16 + c15][(lane >> 4) * 8];
        #pragma unroll
        for (int mi = 0; mi < 4; ++mi)
            #pragma unroll
            for (int ni = 0; ni < 4; ++ni)
                acc[mi][ni] = __builtin_amdgcn_mfma_f32_16x16x32_f16(af[mi], bg[ni], acc[mi][ni], 0, 0, 0);
        __syncthreads();
    }
    float bcol[4];
    if (EPI) {
        #pragma unroll
        for (int ni = 0; ni < 4; ++ni) bcol[ni] = bias[col0 + wn * 64 + ni * 16 + c15];
    }
    #pragma unroll
    for (int mi = 0; mi < 4; ++mi) {
        int rowb = row0 + wm * 64 + mi * 16 + ((lane >> 4) << 2);
        #pragma unroll
        for (int ni = 0; ni < 4; ++ni) {
            int col = col0 + wn * 64 + ni * 16 + c15;
            #pragma unroll
            for (int r = 0; r < 4; ++r) {
                if (rowb + r >= M) continue;
                if (EPI) {
                    float v = acc[mi][ni][r] + bcol[ni];
                    v = v > 0.f ? v : __expf(v) - 1.f;
                    ((float*)Cout)[(size_t)(rowb + r) * D + col] = v;
                } else {
                    ((unsigned short*)Cout)[(size_t)(rowb + r) * D + col] = f2h(acc[mi][ni][r]);
                }
            }
        }
    }
}

// ---------------- attention scores (layer 1) from f16 h ----------------
__global__ __launch_bounds__(256) void attn_scores8(const unsigned short* __restrict__ h,
                                                    const float* __restrict__ a_src,
                                                    const float* __restrict__ a_dst,
                                                    float* __restrict__ es,
                                                    float* __restrict__ ed) {
    int node = blockIdx.x * 4 + (threadIdx.x >> 6);
    int lane = threadIdx.x & 63;
    if (node >= N_NODES) return;
    us4 v = *(const us4*)&h[(size_t)node * D + lane * 4];
    float4 as = *(const float4*)&a_src[lane * 4];
    float4 ad = *(const float4*)&a_dst[lane * 4];
    float vx = h2f(v.x), vy = h2f(v.y), vz = h2f(v.z), vw = h2f(v.w);
    float ps = vx * as.x + vy * as.y + vz * as.z + vw * as.w;
    float pd = vx * ad.x + vy * ad.y + vz * ad.z + vw * ad.w;
    #pragma unroll
    for (int d2 = 1; d2 < 8; d2 <<= 1) {       // 8 lanes per head
        ps += __shfl_xor(ps, d2, 64);
        pd += __shfl_xor(pd, d2, 64);
    }
    if ((lane & 7) == 0) {
        int hd = lane >> 3;
        es[(size_t)node * 8 + hd] = ps;
        ed[(size_t)node * 8 + hd] = pd;
    }
}

// ---------------- per-edge alpha (f16) via online softmax; one wave per node ----------------
template <int H>
__global__ __launch_bounds__(256) void softmax_alpha(const float* __restrict__ es,
                                                     const float* __restrict__ ed,
                                                     const int* __restrict__ off,
                                                     const int* __restrict__ srcs,
                                                     unsigned short* __restrict__ alpha16) {
    int n = blockIdx.x * 4 + (threadIdx.x >> 6);
    if (n >= N_NODES) return;
    int lane = threadIdx.x & 63;
    int begin = off[n], end = off[n + 1];
    int j  = (H == 8) ? (lane >> 3) : lane;
    int hd = (H == 8) ? (lane & 7) : 0;
    const int JS = (H == 8) ? 8 : 64;
    float edn = ed[(size_t)n * H + hd];
    float m = -1e30f, s = 0.f;
    for (int i = begin + j; i < end; i += JS) {
        float e = es[(size_t)srcs[i] * H + hd] + edn;
        e = e > 0.f ? e : NEG_SLOPE * e;
        float nm = fmaxf(m, e);
        s = s * __expf(m - nm) + __expf(e - nm);
        m = nm;
    }
    #pragma unroll
    for (int mask = (H == 8) ? 8 : 1; mask < 64; mask <<= 1) {
        float om = __shfl_xor(m, mask, 64);
        float os = __shfl_xor(s, mask, 64);
        float nm = fmaxf(m, om);
        s = s * __expf(m - nm) + os * __expf(om - nm);
        m = nm;
    }
    float inv_s = 1.f / s;
    for (int i = begin + j; i < end; i += JS) {
        float e = es[(size_t)srcs[i] * H + hd] + edn;
        e = e > 0.f ? e : NEG_SLOPE * e;
        alpha16[(size_t)i * H + hd] = f2h(__expf(e - m) * inv_s);
    }
}

// ---------------- weighted gather of f16 h; one wave per node, 8-deep unroll ----------------
// PLAIN=true: write raw weighted sum (f16), no bias/elu.
// PLAIN=false: add bias + elu, write f16; if SC2, also emit layer-2 scores
//   es2[n] = sum_c z[n,c]*was2[c], ed2 likewise (from f32 pre-rounding values).
template <int H, bool PLAIN, bool SC2>
__global__ __launch_bounds__(256) void gather_agg(const unsigned short* __restrict__ h,
                                                  const unsigned short* __restrict__ alpha16,
                                                  const int* __restrict__ off,
                                                  const int* __restrict__ srcs,
                                                  const float* __restrict__ bias,
                                                  unsigned short* __restrict__ outh,
                                                  const float* __restrict__ was2,
                                                  const float* __restrict__ wad2,
                                                  float* __restrict__ es2,
                                                  float* __restrict__ ed2) {
    int n = blockIdx.x * 4 + (threadIdx.x >> 6);
    if (n >= N_NODES) return;
    int lane = threadIdx.x & 63;
    int begin = off[n], end = off[n + 1];
    int hsel = (H == 8) ? (lane >> 3) : 0;
    float ax = 0.f, ay = 0.f, az = 0.f, aw = 0.f;
    int i = begin;
    for (; i + 7 < end; i += 8) {
        int ss[8]; float w[8]; us4 v[8];
        #pragma unroll
        for (int u = 0; u < 8; ++u) ss[u] = srcs[i + u];
        #pragma unroll
        for (int u = 0; u < 8; ++u) w[u] = h2f(alpha16[(size_t)(i + u) * H + hsel]);
        #pragma unroll
        for (int u = 0; u < 8; ++u) v[u] = *(const us4*)&h[(size_t)ss[u] * D + lane * 4];
        #pragma unroll
        for (int u = 0; u < 8; ++u) {
            ax += h2f(v[u].x) * w[u];
            ay += h2f(v[u].y) * w[u];
            az += h2f(v[u].z) * w[u];
            aw += h2f(v[u].w) * w[u];
        }
    }
    for (; i < end; ++i) {
        int s0 = srcs[i];
        float w0 = h2f(alpha16[(size_t)i * H + hsel]);
        us4 v0 = *(const us4*)&h[(size_t)s0 * D + lane * 4];
        ax += h2f(v0.x) * w0; ay += h2f(v0.y) * w0; az += h2f(v0.z) * w0; aw += h2f(v0.w) * w0;
    }
    float r0, r1, r2, r3;
    if (PLAIN) {
        r0 = ax; r1 = ay; r2 = az; r3 = aw;
    } else {
        float4 b = *(const float4*)&bias[lane * 4];
        r0 = ax + b.x; r1 = ay + b.y; r2 = az + b.z; r3 = aw + b.w;
        r0 = r0 > 0.f ? r0 : __expf(r0) - 1.f;
        r1 = r1 > 0.f ? r1 : __expf(r1) - 1.f;
        r2 = r2 > 0.f ? r2 : __expf(r2) - 1.f;
        r3 = r3 > 0.f ? r3 : __expf(r3) - 1.f;
    }
    us4 o; o.x = f2h(r0); o.y = f2h(r1); o.z = f2h(r2); o.w = f2h(r3);
    *(us4*)&outh[(size_t)n * D + lane * 4] = o;
    if (SC2) {
        float4 ws = *(const float4*)&was2[lane * 4];
        float4 wd = *(const float4*)&wad2[lane * 4];
        float ps = r0 * ws.x + r1 * ws.y + r2 * ws.z + r3 * ws.w;
        float pd = r0 * wd.x + r1 * wd.y + r2 * wd.z + r3 * wd.w;
        #pragma unroll
        for (int mask = 1; mask < 64; mask <<= 1) {
            ps += __shfl_xor(ps, mask, 64);
            pd += __shfl_xor(pd, mask, 64);
        }
        if (lane == 0) { es2[n] = ps; ed2[n] = pd; }
    }
}

// ---------------- launch ----------------
extern "C" void kernel_launch(void* const* d_in, const int* in_sizes, int n_in,
                              void* d_out, int out_size, void* d_ws, size_t ws_size,
                              hipStream_t stream) {
    const float* x        = (const float*)d_in[0];
    const int*   eidx     = (const int*)d_in[1];
    const float* W1       = (const float*)d_in[2];
    const float* att_src1 = (const float*)d_in[3];
    const float* att_dst1 = (const float*)d_in[4];
    const float* b1       = (const float*)d_in[5];
    const float* W2       = (const float*)d_in[6];
    const float* att_src2 = (const float*)d_in[7];
    const float* att_dst2 = (const float*)d_in[8];
    const float* b2       = (const float*)d_in[9];
    float* out = (float*)d_out;

    char* ws = (char*)d_ws;
    size_t o = 0;
    auto take = [&](size_t bytes) { char* p = ws + o; o = (o + bytes + 255) & ~(size_t)255; return p; };
    unsigned short* hb    = (unsigned short*)take((size_t)N_NODES * D * 2);   // h1, later agg2
    unsigned short* zb    = (unsigned short*)take((size_t)N_NODES * D * 2);   // layer-1 output z
    unsigned short* xb    = (unsigned short*)take((size_t)N_NODES * 128 * 2);
    unsigned short* W1t   = (unsigned short*)take((size_t)D * 128 * 2);
    unsigned short* W2t   = (unsigned short*)take((size_t)D * D * 2);
    unsigned short* alpha16 = (unsigned short*)take((size_t)ET * 8 * 2);      // 13.6 MB
    float* es1  = (float*)take((size_t)N_NODES * 8 * 4);
    float* ed1  = (float*)take((size_t)N_NODES * 8 * 4);
    float* es2  = (float*)take((size_t)N_NODES * 4);
    float* ed2  = (float*)take((size_t)N_NODES * 4);
    float* was2 = (float*)take(D * 4);
    float* wad2 = (float*)take(D * 4);
    int*   off  = (int*)take((size_t)(N_NODES + 1) * 4);
    int*   cur  = (int*)take((size_t)N_NODES * 4);
    int*   srcs = (int*)take((size_t)ET * 4);
    int*   deg  = (int*)take((size_t)N_NODES * 4);
    int*   bsum = (int*)take(256);
    int*   carry= (int*)take(256);
    int*   flag = (int*)take(256);

    hipMemsetAsync(deg, 0, (size_t)N_NODES * 4, stream);
    hipMemsetAsync(flag, 0, 4, stream);

    const int EB = (ET + 255) / 256;
    detect_fmt<<<4, 256, 0, stream>>>(eidx, flag);
    count_deg<<<EB, 256, 0, stream>>>(eidx, flag, deg);
    scan_block_sums<<<NB_SCAN, 256, 0, stream>>>(deg, bsum);
    scan_carry<<<1, 64, 0, stream>>>(bsum, carry, off);
    scan_write<<<NB_SCAN, 256, 0, stream>>>(deg, carry, off, cur);
    scatter_edges<<<EB, 256, 0, stream>>>(eidx, flag, cur, srcs);

    conv_w_t<<<128, 256, 0, stream>>>(W1, W1t, 128);
    conv_w_t<<<256, 256, 0, stream>>>(W2, W2t, 256);
    wvec2<<<1, 256, 0, stream>>>(W2, att_src2, att_dst2, was2, wad2);
    conv_f32_f16<<<(N_NODES * 128 / 4 + 255) / 256, 256, 0, stream>>>(x, xb, N_NODES * 128 / 4);

    const int NBLK = (N_NODES + 3) / 4;
    const dim3 GG(2, (N_NODES + 127) / 128);
    // ---- layer 1 ----
    gemm_f16<false><<<GG, 256, 0, stream>>>(xb, W1t, hb, nullptr, N_NODES, 128);
    attn_scores8<<<NBLK, 256, 0, stream>>>(hb, att_src1, att_dst1, es1, ed1);
    softmax_alpha<8><<<NBLK, 256, 0, stream>>>(es1, ed1, off, srcs, alpha16);
    gather_agg<8, false, true><<<NBLK, 256, 0, stream>>>(hb, alpha16, off, srcs, b1, zb,
                                                         was2, wad2, es2, ed2);
    // ---- layer 2 (aggregate in input space, then project) ----
    softmax_alpha<1><<<NBLK, 256, 0, stream>>>(es2, ed2, off, srcs, alpha16);
    gather_agg<1, true, false><<<NBLK, 256, 0, stream>>>(zb, alpha16, off, srcs, nullptr, hb,
                                                         nullptr, nullptr, nullptr, nullptr);
    gemm_f16<true><<<GG, 256, 0, stream>>>(hb, W2t, out, b2, N_NODES, 256);
}